// Round 1
// baseline (265.450 us; speedup 1.0000x reference)
//
#include <hip/hip_runtime.h>

#define E_DIM 1024
#define NH 16
#define DH 64
#define BSEG 8
#define LQ 512
#define LKV 1024

typedef short bf16x8 __attribute__((ext_vector_type(8)));
typedef float f32x4 __attribute__((ext_vector_type(4)));
typedef unsigned short u16;

// round-to-nearest-even fp32 -> bf16 bits
__device__ __forceinline__ u16 f2bf(float x) {
    unsigned u = __float_as_uint(x);
    u += 0x7FFF + ((u >> 16) & 1);
    return (u16)(u >> 16);
}

// async global->LDS, 16B per lane; lds dest wave-uniform base + lane*16
__device__ __forceinline__ void async16(const void* g, const void* l) {
    __builtin_amdgcn_global_load_lds(
        (const __attribute__((address_space(1))) unsigned int*)g,
        (__attribute__((address_space(3))) unsigned int*)l, 16, 0, 0);
}

// ---------------------------------------------------------------------------
// Fused fp32->bf16 convert for all 4 inputs (one launch).
// ---------------------------------------------------------------------------
__global__ __launch_bounds__(256) void cvt_all_kernel(
    const float* __restrict__ inputs, const float* __restrict__ queries,
    const float* __restrict__ w_in, const float* __restrict__ w_out,
    u16* __restrict__ ib, u16* __restrict__ qb,
    u16* __restrict__ wib, u16* __restrict__ wob)
{
    int blk = blockIdx.x;
    const float* s; u16* d; int base;
    if (blk < 8192)        { s = inputs;  d = ib;  base = blk; }
    else if (blk < 12288)  { s = queries; d = qb;  base = blk - 8192; }
    else if (blk < 15360)  { s = w_in;    d = wib; base = blk - 12288; }
    else                   { s = w_out;   d = wob; base = blk - 15360; }
    int i = base * 256 + threadIdx.x;
    float4 v = ((const float4*)s)[i];
    ushort4 o;
    o.x = f2bf(v.x); o.y = f2bf(v.y); o.z = f2bf(v.z); o.w = f2bf(v.w);
    ((ushort4*)d)[i] = o;
}

// ---------------------------------------------------------------------------
// Fused Q/K/V projection GEMM. 128x128 tile, BK=32, 256 threads, XCD-compact
// 1D grid (unchanged geometry) — NOW with:
//  * double-buffered LDS + T3 "minimum 2-phase" pipeline: stage(next tile)
//    issued BEFORE ds_read+MFMA of current tile; ONE __syncthreads per
//    K-step (its vmcnt(0) drains loads that had a full compute phase to
//    land) instead of the old stage->drain->compute (fully exposed latency).
//  * K/Q blocks compute the TRANSPOSED product via swapped MFMA operands
//    (mfma(wf, af)): acc regs then hold 4 consecutive d for a fixed token,
//    which is contiguous in frag16 -> ushort4 stores (4x fewer store
//    instructions, 8B each) instead of 64 scattered 2B stores/thread.
//    V blocks keep original operand order (sigma' layout packs over tokens).
// Layouts of Qf/Kf/Vf are bit-identical to before; attn kernel unchanged.
// ---------------------------------------------------------------------------
__global__ __launch_bounds__(256) void proj_gemm_kernel(
    const u16* __restrict__ inputs_b, const u16* __restrict__ queries_b,
    const u16* __restrict__ w_in_b, const float* __restrict__ b_in,
    u16* __restrict__ Kf, u16* __restrict__ Qf, u16* __restrict__ Vf)
{
    __shared__ u16 As[2][128 * 32];
    __shared__ u16 Ws[2][128 * 32];

    const int bid = blockIdx.x;
    const bool isQ = (bid >= 1024);
    const int x = bid & 7;
    int bx, by;
    if (!isQ) { int i = bid >> 3;          bx = i >> 3; by = x * 8 + (i & 7); }
    else      { int i = (bid - 1024) >> 3; bx = i >> 2; by = x * 4 + (i & 3); }

    const bool isV = (!isQ) && (bx >= 8);   // whole block is V (cols >= 1024)

    const u16* A = isQ ? queries_b : inputs_b;
    const u16* W = w_in_b + (isQ ? 0 : (size_t)E_DIM * E_DIM);
    const float* bias = b_in + (isQ ? 0 : E_DIM);
    const int m_blk = by * 128;
    const int n_blk = bx * 128;
    const int K = E_DIM;

    const int tid = threadIdx.x;
    const int l = tid & 63;
    const int w = tid >> 6;
    const int m0 = (w & 1) * 64;
    const int n0 = (w >> 1) * 64;
    const int quad = l >> 4;
    const int c = l & 15;

    f32x4 acc[4][4];
    #pragma unroll
    for (int i = 0; i < 4; ++i)
        #pragma unroll
        for (int j = 0; j < 4; ++j)
            acc[i][j] = (f32x4){0.f, 0.f, 0.f, 0.f};

    const int srow = l >> 2;
    const int skoff = (l & 3) * 8;
    const u16* Ag1 = A + (size_t)(m_blk + w * 16 + srow) * K + skoff;
    const u16* Ag2 = A + (size_t)(m_blk + (w + 4) * 16 + srow) * K + skoff;
    const u16* Wg1 = W + (size_t)(n_blk + w * 16 + srow) * K + skoff;
    const u16* Wg2 = W + (size_t)(n_blk + (w + 4) * 16 + srow) * K + skoff;

    auto stage = [&](int b, int k0) {
        async16(Ag1 + k0, As[b] + (size_t)w * 512);
        async16(Ag2 + k0, As[b] + (size_t)(w + 4) * 512);
        async16(Wg1 + k0, Ws[b] + (size_t)w * 512);
        async16(Wg2 + k0, Ws[b] + (size_t)(w + 4) * 512);
    };

    // prologue: stage tile 0, drain, enter pipelined loop
    stage(0, 0);
    __syncthreads();

    int cur = 0;
    for (int k0 = 0; k0 < K; k0 += 32) {
        if (k0 + 32 < K) stage(cur ^ 1, k0 + 32);   // prefetch next tile

        bf16x8 af[4], wf[4];
        #pragma unroll
        for (int t = 0; t < 4; ++t) {
            af[t] = *(const bf16x8*)&As[cur][(m0 + t * 16 + c) * 32 + quad * 8];
            wf[t] = *(const bf16x8*)&Ws[cur][(n0 + t * 16 + c) * 32 + quad * 8];
        }
        if (isV) {
            #pragma unroll
            for (int i = 0; i < 4; ++i)
                #pragma unroll
                for (int j = 0; j < 4; ++j)
                    acc[i][j] = __builtin_amdgcn_mfma_f32_16x16x32_bf16(
                        af[i], wf[j], acc[i][j], 0, 0, 0);
        } else {
            // swapped operands: D rows = W-cols (d), D cols = tokens
            #pragma unroll
            for (int i = 0; i < 4; ++i)
                #pragma unroll
                for (int j = 0; j < 4; ++j)
                    acc[i][j] = __builtin_amdgcn_mfma_f32_16x16x32_bf16(
                        wf[j], af[i], acc[i][j], 0, 0, 0);
        }
        __syncthreads();   // vmcnt(0) drains the prefetch issued above
        cur ^= 1;
    }

    if (!isV) {
        // K/Q epilogue, swapped layout: lane holds d = colb..colb+3 for
        // token = m_blk+m0+i*16+c  ->  contiguous ushort4 in frag16.
        u16* dst = isQ ? Qf : Kf;
        #pragma unroll
        for (int jj = 0; jj < 4; ++jj) {
            const int colb = n_blk + n0 + jj * 16 + quad * 4;
            const float4 bv = *(const float4*)&bias[colb];
            const int hh = colb >> 6;
            const int d  = colb & 63;
            const size_t doff = (size_t)(d >> 3) * 128 + (size_t)c * 8 + (d & 7);
            #pragma unroll
            for (int i = 0; i < 4; ++i) {
                const int t16 = ((m_blk + m0) >> 4) + i;
                ushort4 pk;
                pk.x = f2bf(acc[i][jj][0] + bv.x);
                pk.y = f2bf(acc[i][jj][1] + bv.y);
                pk.z = f2bf(acc[i][jj][2] + bv.z);
                pk.w = f2bf(acc[i][jj][3] + bv.w);
                *(ushort4*)(dst + ((size_t)(t16 * NH + hh)) * 1024 + doff) = pk;
            }
        }
    } else {
        // V epilogue: original operand order, sigma'-frag pack (unchanged).
        #pragma unroll
        for (int jj = 0; jj < 4; ++jj) {
            int col = n_blk + n0 + jj * 16 + c;
            float bv = bias[col];
            int vcol = col - 1024;
            int hv = vcol >> 6, d = vcol & 63;
            int td = d >> 4, ct = d & 15;
            #pragma unroll
            for (int i = 0; i < 4; ++i) {
                int tok = m_blk + m0 + i * 16;
                int g32 = tok >> 5;
                int jo = (tok & 16) >> 2;          // 0 or 4
                ushort4 pk;
                pk.x = f2bf(acc[i][jj][0] + bv);
                pk.y = f2bf(acc[i][jj][1] + bv);
                pk.z = f2bf(acc[i][jj][2] + bv);
                pk.w = f2bf(acc[i][jj][3] + bv);
                *(ushort4*)(Vf + ((size_t)(g32 * NH + hv)) * 2048
                            + (size_t)((td * 4 + quad) * 16 + ct) * 8 + jo) = pk;
            }
        }
    }
}

// ---------------------------------------------------------------------------
// Attention, S^T formulation; frag-ordered operands; no LDS/barriers.
// (unchanged this round)
// ---------------------------------------------------------------------------
struct KVfrags { bf16x8 kf[4][2]; bf16x8 vf[2][4]; };

__global__ __launch_bounds__(256) void attn_kernel(
    const u16* __restrict__ Qf, const u16* __restrict__ Kf,
    const u16* __restrict__ Vf, u16* __restrict__ Ob)
{
    const int tid = threadIdx.x;
    const int l = tid & 63;
    const int w = tid >> 6;
    const int quad = l >> 4;
    const int c = l & 15;
    const int bid = blockIdx.x;
    const int h = bid & 15;
    const int b = (bid >> 4) & 7;
    const int qt = bid >> 7;
    const int q0 = b * LQ + qt * 64 + w * 16;
    const float C1 = 0.18033688011112042f;   // (1/8)*log2(e)

    bf16x8 qf[2];
    {
        size_t qb = ((size_t)((q0 >> 4) * NH + h)) * 1024 + (size_t)l * 8;
        qf[0] = *(const bf16x8*)(Qf + qb);
        qf[1] = *(const bf16x8*)(Qf + qb + 512);
    }

    f32x4 o[4];
    #pragma unroll
    for (int td = 0; td < 4; ++td) o[td] = (f32x4){0.f, 0.f, 0.f, 0.f};
    float m_i = -1e30f, l_i = 0.f;

    auto load_kv = [&](int kv0, KVfrags& dst) {
        const int kvg = b * LKV + kv0;
        #pragma unroll
        for (int nt = 0; nt < 4; ++nt) {
            size_t kb = ((size_t)((((kvg >> 4) + nt) * NH) + h)) * 1024 + (size_t)l * 8;
            dst.kf[nt][0] = *(const bf16x8*)(Kf + kb);
            dst.kf[nt][1] = *(const bf16x8*)(Kf + kb + 512);
        }
        #pragma unroll
        for (int g = 0; g < 2; ++g) {
            size_t vb = ((size_t)((((kvg >> 5) + g) * NH) + h)) * 2048 + (size_t)l * 8;
            #pragma unroll
            for (int td = 0; td < 4; ++td)
                dst.vf[g][td] = *(const bf16x8*)(Vf + vb + td * 512);
        }
    };

    auto step = [&](KVfrags& cv) {
        f32x4 s[4];
        #pragma unroll
        for (int nt = 0; nt < 4; ++nt) s[nt] = (f32x4){0.f, 0.f, 0.f, 0.f};
        #pragma unroll
        for (int nt = 0; nt < 4; ++nt)
            #pragma unroll
            for (int hk = 0; hk < 2; ++hk)
                s[nt] = __builtin_amdgcn_mfma_f32_16x16x32_bf16(
                    cv.kf[nt][hk], qf[hk], s[nt], 0, 0, 0);

        float vm = -1e30f;
        #pragma unroll
        for (int nt = 0; nt < 4; ++nt)
            #pragma unroll
            for (int r = 0; r < 4; ++r) vm = fmaxf(vm, s[nt][r]);
        vm = fmaxf(vm, __shfl_xor(vm, 16, 64));
        vm = fmaxf(vm, __shfl_xor(vm, 32, 64));
        float mnew = fmaxf(m_i, vm);
        float alpha = __builtin_amdgcn_exp2f((m_i - mnew) * C1);
        m_i = mnew;

        float p[4][4];
        float rs = 0.f;
        #pragma unroll
        for (int nt = 0; nt < 4; ++nt)
            #pragma unroll
            for (int r = 0; r < 4; ++r) {
                p[nt][r] = __builtin_amdgcn_exp2f((s[nt][r] - mnew) * C1);
                rs += p[nt][r];
            }
        rs += __shfl_xor(rs, 16, 64);
        rs += __shfl_xor(rs, 32, 64);
        l_i = l_i * alpha + rs;

        float ar[4];
        #pragma unroll
        for (int r = 0; r < 4; ++r) ar[r] = __shfl(alpha, quad * 4 + r, 16);
        #pragma unroll
        for (int td = 0; td < 4; ++td)
            #pragma unroll
            for (int r = 0; r < 4; ++r) o[td][r] *= ar[r];

        bf16x8 af[2];
        #pragma unroll
        for (int g = 0; g < 2; ++g)
            #pragma unroll
            for (int r = 0; r < 4; ++r) {
                af[g][r]     = (short)f2bf(p[2 * g][r]);
                af[g][4 + r] = (short)f2bf(p[2 * g + 1][r]);
            }

        #pragma unroll
        for (int g = 0; g < 2; ++g)
            #pragma unroll
            for (int td = 0; td < 4; ++td)
                o[td] = __builtin_amdgcn_mfma_f32_16x16x32_bf16(
                    af[g], cv.vf[g][td], o[td], 0, 0, 0);
    };

    KVfrags bufA, bufB;
    load_kv(0, bufA);
    #pragma unroll
    for (int it = 0; it < 16; it += 2) {
        if (it + 1 < 16) load_kv((it + 1) * 64, bufB);
        step(bufA);
        if (it + 2 < 16) load_kv((it + 2) * 64, bufA);
        if (it + 1 < 16) step(bufB);
    }

    float invl = 1.f / l_i;
    float ir[4];
    #pragma unroll
    for (int r = 0; r < 4; ++r) ir[r] = __shfl(invl, quad * 4 + r, 16);
    #pragma unroll
    for (int td = 0; td < 4; ++td)
        #pragma unroll
        for (int r = 0; r < 4; ++r)
            Ob[(size_t)(q0 + quad * 4 + r) * E_DIM + h * 64 + td * 16 + c] =
                f2bf(o[td][r] * ir[r]);
}

// ---------------------------------------------------------------------------
// Output projection: out[4096,1024] = Ob @ w_out^T + b_out (fp32 out).
// Same 2-phase double-buffer pipeline + swapped MFMA operands so the lane
// holds 4 consecutive output columns -> float4 stores.
// ---------------------------------------------------------------------------
__global__ __launch_bounds__(256) void out_gemm_kernel(
    const u16* __restrict__ A, const u16* __restrict__ W,
    const float* __restrict__ bias, float* __restrict__ Cf)
{
    __shared__ u16 As[2][128 * 32];
    __shared__ u16 Ws[2][128 * 32];

    const int K = E_DIM, N = E_DIM;
    const int bid = blockIdx.x;
    const int x = bid & 7;
    const int i_ = bid >> 3;            // 0..31
    const int m_blk = (x * 4 + (i_ & 3)) * 128;
    const int n_blk = (i_ >> 2) * 128;

    const int tid = threadIdx.x;
    const int l = tid & 63;
    const int w = tid >> 6;
    const int m0 = (w & 1) * 64;
    const int n0 = (w >> 1) * 64;
    const int quad = l >> 4;
    const int c = l & 15;

    f32x4 acc[4][4];
    #pragma unroll
    for (int i = 0; i < 4; ++i)
        #pragma unroll
        for (int j = 0; j < 4; ++j)
            acc[i][j] = (f32x4){0.f, 0.f, 0.f, 0.f};

    const int srow = l >> 2;
    const int skoff = (l & 3) * 8;
    const u16* Ag1 = A + (size_t)(m_blk + w * 16 + srow) * K + skoff;
    const u16* Ag2 = A + (size_t)(m_blk + (w + 4) * 16 + srow) * K + skoff;
    const u16* Wg1 = W + (size_t)(n_blk + w * 16 + srow) * K + skoff;
    const u16* Wg2 = W + (size_t)(n_blk + (w + 4) * 16 + srow) * K + skoff;

    auto stage = [&](int b, int k0) {
        async16(Ag1 + k0, As[b] + (size_t)w * 512);
        async16(Ag2 + k0, As[b] + (size_t)(w + 4) * 512);
        async16(Wg1 + k0, Ws[b] + (size_t)w * 512);
        async16(Wg2 + k0, Ws[b] + (size_t)(w + 4) * 512);
    };

    stage(0, 0);
    __syncthreads();

    int cur = 0;
    for (int k0 = 0; k0 < K; k0 += 32) {
        if (k0 + 32 < K) stage(cur ^ 1, k0 + 32);

        bf16x8 af[4], wf[4];
        #pragma unroll
        for (int t = 0; t < 4; ++t) {
            af[t] = *(const bf16x8*)&As[cur][(m0 + t * 16 + c) * 32 + quad * 8];
            wf[t] = *(const bf16x8*)&Ws[cur][(n0 + t * 16 + c) * 32 + quad * 8];
        }
        #pragma unroll
        for (int i = 0; i < 4; ++i)
            #pragma unroll
            for (int j = 0; j < 4; ++j)
                acc[i][j] = __builtin_amdgcn_mfma_f32_16x16x32_bf16(
                    wf[j], af[i], acc[i][j], 0, 0, 0);
        __syncthreads();
        cur ^= 1;
    }

    #pragma unroll
    for (int j = 0; j < 4; ++j) {
        const int colb = n_blk + n0 + j * 16 + quad * 4;
        const float4 bv = *(const float4*)&bias[colb];
        #pragma unroll
        for (int i = 0; i < 4; ++i) {
            const int row = m_blk + m0 + i * 16 + c;
            float4 o4;
            o4.x = acc[i][j][0] + bv.x;
            o4.y = acc[i][j][1] + bv.y;
            o4.z = acc[i][j][2] + bv.z;
            o4.w = acc[i][j][3] + bv.w;
            *(float4*)&Cf[(size_t)row * N + colb] = o4;
        }
    }
}

// ---------------------------------------------------------------------------
extern "C" void kernel_launch(void* const* d_in, const int* in_sizes, int n_in,
                              void* d_out, int out_size, void* d_ws, size_t ws_size,
                              hipStream_t stream) {
    const float* inputs  = (const float*)d_in[0];   // [8192,1024]
    const float* queries = (const float*)d_in[1];   // [4096,1024]
    const float* w_in    = (const float*)d_in[2];   // [3072,1024]
    const float* b_in    = (const float*)d_in[3];   // [3072]
    const float* w_out   = (const float*)d_in[4];   // [1024,1024]
    const float* b_out   = (const float*)d_in[5];   // [1024]
    float* out = (float*)d_out;                     // [4096,1024] fp32

    const int NQ = BSEG * LQ;    // 4096
    const int NKV = BSEG * LKV;  // 8192

    // workspace: 80 MB
    u16* inputs_b  = (u16*)d_ws;                                   // 16 MB
    u16* queries_b = inputs_b  + (size_t)NKV * E_DIM;              //  8 MB
    u16* w_in_b    = queries_b + (size_t)NQ * E_DIM;               //  6 MB
    u16* w_out_b   = w_in_b    + (size_t)3 * E_DIM * E_DIM;        //  2 MB
    u16* Qf        = w_out_b   + (size_t)E_DIM * E_DIM;            //  8 MB
    u16* Kf        = Qf        + (size_t)NQ * E_DIM;               // 16 MB
    u16* Vf        = Kf        + (size_t)NKV * E_DIM;              // 16 MB
    u16* Ob        = Vf        + (size_t)NKV * E_DIM;              //  8 MB

    dim3 blk(256);

    cvt_all_kernel<<<16384, blk, 0, stream>>>(
        inputs, queries, w_in, w_out, inputs_b, queries_b, w_in_b, w_out_b);

    proj_gemm_kernel<<<1280, blk, 0, stream>>>(
        inputs_b, queries_b, w_in_b, b_in, Kf, Qf, Vf);

    attn_kernel<<<1024, blk, 0, stream>>>(Qf, Kf, Vf, Ob);

    out_gemm_kernel<<<256, blk, 0, stream>>>(
        Ob, w_out_b, b_out, out);
}